// Round 4
// baseline (78.016 us; speedup 1.0000x reference)
//
#include <hip/hip_runtime.h>

#define EPS 1e-5f

typedef __attribute__((ext_vector_type(4))) float f32x4;
typedef __attribute__((ext_vector_type(8))) _Float16 f16x8;
typedef __attribute__((ext_vector_type(4))) _Float16 f16x4;

// ============ kernel 1: prep (BN-fold, offsets) ∥ convxT (transpose x) ============
__global__ __launch_bounds__(256) void prep_conv_kernel(
    const int* __restrict__ ld,
    const float* __restrict__ Wl, const float* __restrict__ bl,
    const float* __restrict__ gl, const float* __restrict__ betal,
    const float* __restrict__ ml, const float* __restrict__ vl,
    const float* __restrict__ W1, const float* __restrict__ b1,
    const float* __restrict__ g1, const float* __restrict__ beta1,
    const float* __restrict__ m1, const float* __restrict__ v1,
    const float* __restrict__ W2, const float* __restrict__ b2,
    const float* __restrict__ g2, const float* __restrict__ beta2,
    const float* __restrict__ m2, const float* __restrict__ v2,
    int* __restrict__ offs, float* __restrict__ c1, float* __restrict__ cf,
    _Float16* __restrict__ W1h, _Float16* __restrict__ Wch,
    const float* __restrict__ x, _Float16* __restrict__ XT, int M)
{
    __shared__ __align__(16) _Float16 Tt[128][80];
    int t = threadIdx.x;
    if (blockIdx.x < 256) {
        // ---- convxT: xT[128][M] fp16 from x[M][128] fp32 ----
        int m0 = blockIdx.x * 64;
        #pragma unroll
        for (int p = 0; p < 8; ++p) {
            int idx = t + p * 256;
            int m = idx >> 5;
            int f = (idx & 31) * 4;
            float4 v = *(const float4*)&x[(size_t)(m0 + m) * 128 + f];
            Tt[f + 0][m] = (_Float16)v.x; Tt[f + 1][m] = (_Float16)v.y;
            Tt[f + 2][m] = (_Float16)v.z; Tt[f + 3][m] = (_Float16)v.w;
        }
        __syncthreads();
        #pragma unroll
        for (int p = 0; p < 4; ++p) {
            int idx = t + p * 256;
            int f = idx >> 3;
            int m8 = (idx & 7) * 8;
            uint4 v = *(const uint4*)&Tt[f][m8];
            *(uint4*)&XT[(size_t)f * M + m0 + m8] = v;
        }
    } else {
        // ---- prep ----
        int b = blockIdx.x - 256;
        int gt = b * 256 + t;
        const int gsize = 64 * 256;
        if (b == 0) {
            if (t < 64) {
                int s = 0;
                for (int i = 0; i < t; ++i) s += ld[i];
                offs[t] = s;
            }
            if (t < 128) {
                float s1 = g1[t] * rsqrtf(v1[t] + EPS);
                c1[t] = (b1[t] - m1[t]) * s1 + beta1[t];
            }
            if (t < 256) {
                float s2 = g2[t] * rsqrtf(v2[t] + EPS);
                float sl = gl[t] * rsqrtf(vl[t] + EPS);
                cf[t] = (b2[t] - m2[t]) * s2 + beta2[t] + (bl[t] - ml[t]) * sl + betal[t];
            }
        }
        for (int idx = gt; idx < 128 * 128; idx += gsize) {
            int n = idx >> 7;
            float s1 = g1[n] * rsqrtf(v1[n] + EPS);
            W1h[idx] = (_Float16)(W1[idx] * s1);
        }
        for (int idx = gt; idx < 256 * 256; idx += gsize) {
            int n = idx >> 8, k = idx & 255;
            float v;
            if (k < 128) {
                float s2 = g2[n] * rsqrtf(v2[n] + EPS);
                v = W2[n * 128 + k] * s2;
            } else {
                float sl = gl[n] * rsqrtf(vl[n] + EPS);
                v = Wl[n * 128 + (k - 128)] * sl;
            }
            Wch[idx] = (_Float16)v;
        }
    }
}

// ============ kernel 2: fused agg1 + lin1 -> h2T (transposed fp16) ============
// phase A: h1[m][n] = sum_k am[m][k] * XT[n][k]   (64 rows x 128 feats per block)
// phase B: h2T[n][m] = relu(sum_k h1[m][k]*W1h[n][k] + c1[n])
__global__ __launch_bounds__(256) void fused1_kernel(
    const float* __restrict__ am, const _Float16* __restrict__ XT,
    const int* __restrict__ ld, const int* __restrict__ offs,
    const _Float16* __restrict__ Wh, const float* __restrict__ bias,
    _Float16* __restrict__ outT, int M)
{
    int g = blockIdx.y;
    int l = ld[g];
    int r0 = blockIdx.x * 64;
    if (r0 >= l) return;
    int off = offs[g];
    const float* A = am + (size_t)g * 512 * 512;

    __shared__ __align__(16) _Float16 stage[192][40]; // A: rows 0-127 XT tile, 128-191 am tile; B: rows 0-127 W chunk
    __shared__ __align__(16) _Float16 Hs[64][136];

    int tid = threadIdx.x;
    int lane = tid & 63;
    int w = tid >> 6;
    int l15 = lane & 15;
    int l4 = lane >> 4;

    f32x4 acc[2][4];
    #pragma unroll
    for (int i = 0; i < 2; ++i)
        #pragma unroll
        for (int j = 0; j < 4; ++j)
            acc[i][j] = (f32x4){0.f, 0.f, 0.f, 0.f};

    uint4 pa[2]; float4 pb[2];
    #pragma unroll
    for (int p = 0; p < 2; ++p) {
        int idx = tid + p * 256;
        pa[p] = *(const uint4*)&XT[(size_t)(idx >> 2) * M + off + (idx & 3) * 8];
        pb[p] = *(const float4*)(A + (size_t)(r0 + (idx >> 3)) * 512 + (idx & 7) * 4);
    }

    int nk = l >> 5;
    for (int s = 0; s < nk; ++s) {
        #pragma unroll
        for (int p = 0; p < 2; ++p) {
            int idx = tid + p * 256;
            *(uint4*)&stage[idx >> 2][(idx & 3) * 8] = pa[p];
            f16x4 b;
            b[0] = (_Float16)pb[p].x; b[1] = (_Float16)pb[p].y;
            b[2] = (_Float16)pb[p].z; b[3] = (_Float16)pb[p].w;
            *(f16x4*)&stage[128 + (idx >> 3)][(idx & 7) * 4] = b;
        }
        if (s + 1 < nk) {
            int k0 = (s + 1) * 32;
            #pragma unroll
            for (int p = 0; p < 2; ++p) {
                int idx = tid + p * 256;
                pa[p] = *(const uint4*)&XT[(size_t)(idx >> 2) * M + off + k0 + (idx & 3) * 8];
                pb[p] = *(const float4*)(A + (size_t)(r0 + (idx >> 3)) * 512 + k0 + (idx & 7) * 4);
            }
        }
        __syncthreads();
        f16x8 a[2], b[4];
        #pragma unroll
        for (int i = 0; i < 2; ++i)
            a[i] = *(const f16x8*)&stage[w * 32 + i * 16 + l15][l4 * 8];
        #pragma unroll
        for (int j = 0; j < 4; ++j)
            b[j] = *(const f16x8*)&stage[128 + j * 16 + l15][l4 * 8];
        #pragma unroll
        for (int i = 0; i < 2; ++i)
            #pragma unroll
            for (int j = 0; j < 4; ++j)
                acc[i][j] = __builtin_amdgcn_mfma_f32_16x16x32_f16(a[i], b[j], acc[i][j], 0, 0, 0);
        __syncthreads();
    }
    // spill h1 tile -> Hs[row][feat]
    #pragma unroll
    for (int i = 0; i < 2; ++i) {
        int n0 = w * 32 + i * 16 + l4 * 4;
        #pragma unroll
        for (int j = 0; j < 4; ++j) {
            int r = j * 16 + l15;
            f16x4 o;
            o[0] = (_Float16)acc[i][j][0]; o[1] = (_Float16)acc[i][j][1];
            o[2] = (_Float16)acc[i][j][2]; o[3] = (_Float16)acc[i][j][3];
            *(f16x4*)&Hs[r][n0] = o;
        }
    }

    // ---- phase B: lin1 over K=128 ----
    f32x4 acc2[4][2];
    #pragma unroll
    for (int i = 0; i < 4; ++i)
        #pragma unroll
        for (int j = 0; j < 2; ++j)
            acc2[i][j] = (f32x4){0.f, 0.f, 0.f, 0.f};

    uint4 pw[2];
    #pragma unroll
    for (int p = 0; p < 2; ++p) {
        int idx = tid + p * 256;
        pw[p] = *(const uint4*)&Wh[(size_t)(idx >> 2) * 128 + (idx & 3) * 8];
    }
    #pragma unroll
    for (int s = 0; s < 4; ++s) {
        #pragma unroll
        for (int p = 0; p < 2; ++p) {
            int idx = tid + p * 256;
            *(uint4*)&stage[idx >> 2][(idx & 3) * 8] = pw[p];
        }
        if (s + 1 < 4) {
            int k0 = (s + 1) * 32;
            #pragma unroll
            for (int p = 0; p < 2; ++p) {
                int idx = tid + p * 256;
                pw[p] = *(const uint4*)&Wh[(size_t)(idx >> 2) * 128 + k0 + (idx & 3) * 8];
            }
        }
        __syncthreads();
        f16x8 a[4], b[2];
        #pragma unroll
        for (int i = 0; i < 4; ++i)
            a[i] = *(const f16x8*)&Hs[i * 16 + l15][s * 32 + l4 * 8];
        #pragma unroll
        for (int j = 0; j < 2; ++j)
            b[j] = *(const f16x8*)&stage[w * 32 + j * 16 + l15][l4 * 8];
        #pragma unroll
        for (int i = 0; i < 4; ++i)
            #pragma unroll
            for (int j = 0; j < 2; ++j)
                acc2[i][j] = __builtin_amdgcn_mfma_f32_16x16x32_f16(a[i], b[j], acc2[i][j], 0, 0, 0);
        __syncthreads();
    }
    // write transposed: n = w*32 + j*16 + l15, m = off + r0 + i*16 + l4*4 + r
    #pragma unroll
    for (int j = 0; j < 2; ++j) {
        int n = w * 32 + j * 16 + l15;
        float bv = bias[n];
        #pragma unroll
        for (int i = 0; i < 4; ++i) {
            f16x4 o;
            #pragma unroll
            for (int r = 0; r < 4; ++r) {
                float v = acc2[i][j][r] + bv;
                o[r] = (_Float16)(v > 0.f ? v : 0.f);
            }
            *(f16x4*)&outT[(size_t)n * M + off + r0 + i * 16 + l4 * 4] = o;
        }
    }
}

// ============ kernel 3: fused agg2 + final -> out (fp32, leaky) ============
// phase A: h3[m][n] = sum_k am[m][k] * h2T[n][k]
// phase B: out[m][n] = leaky(sum_{k<128} h3[m][k]*Wch[n][k] + sum_k x[m][k]*Wch[n][128+k] + cf[n])
__global__ __launch_bounds__(256) void fused2_kernel(
    const float* __restrict__ am, const _Float16* __restrict__ XT,
    const int* __restrict__ ld, const int* __restrict__ offs,
    const float* __restrict__ x, const _Float16* __restrict__ Wh,
    const float* __restrict__ bias, float* __restrict__ out, int M)
{
    int g = blockIdx.y;
    int l = ld[g];
    int r0 = blockIdx.x * 64;
    if (r0 >= l) return;
    int off = offs[g];
    const float* A = am + (size_t)g * 512 * 512;

    __shared__ __align__(16) _Float16 stage[256][40]; // A: 0-127 XT tile, 128-191 am tile; B: 0-255 W chunk
    __shared__ __align__(16) _Float16 HX[64][264];    // cols 0-127 agg feats, 128-255 x feats

    int tid = threadIdx.x;
    int lane = tid & 63;
    int w = tid >> 6;
    int l15 = lane & 15;
    int l4 = lane >> 4;

    f32x4 acc[2][4];
    #pragma unroll
    for (int i = 0; i < 2; ++i)
        #pragma unroll
        for (int j = 0; j < 4; ++j)
            acc[i][j] = (f32x4){0.f, 0.f, 0.f, 0.f};

    uint4 pa[2]; float4 pb[2];
    #pragma unroll
    for (int p = 0; p < 2; ++p) {
        int idx = tid + p * 256;
        pa[p] = *(const uint4*)&XT[(size_t)(idx >> 2) * M + off + (idx & 3) * 8];
        pb[p] = *(const float4*)(A + (size_t)(r0 + (idx >> 3)) * 512 + (idx & 7) * 4);
    }

    int nk = l >> 5;
    for (int s = 0; s < nk; ++s) {
        #pragma unroll
        for (int p = 0; p < 2; ++p) {
            int idx = tid + p * 256;
            *(uint4*)&stage[idx >> 2][(idx & 3) * 8] = pa[p];
            f16x4 b;
            b[0] = (_Float16)pb[p].x; b[1] = (_Float16)pb[p].y;
            b[2] = (_Float16)pb[p].z; b[3] = (_Float16)pb[p].w;
            *(f16x4*)&stage[128 + (idx >> 3)][(idx & 7) * 4] = b;
        }
        if (s + 1 < nk) {
            int k0 = (s + 1) * 32;
            #pragma unroll
            for (int p = 0; p < 2; ++p) {
                int idx = tid + p * 256;
                pa[p] = *(const uint4*)&XT[(size_t)(idx >> 2) * M + off + k0 + (idx & 3) * 8];
                pb[p] = *(const float4*)(A + (size_t)(r0 + (idx >> 3)) * 512 + k0 + (idx & 7) * 4);
            }
        }
        __syncthreads();
        f16x8 a[2], b[4];
        #pragma unroll
        for (int i = 0; i < 2; ++i)
            a[i] = *(const f16x8*)&stage[w * 32 + i * 16 + l15][l4 * 8];
        #pragma unroll
        for (int j = 0; j < 4; ++j)
            b[j] = *(const f16x8*)&stage[128 + j * 16 + l15][l4 * 8];
        #pragma unroll
        for (int i = 0; i < 2; ++i)
            #pragma unroll
            for (int j = 0; j < 4; ++j)
                acc[i][j] = __builtin_amdgcn_mfma_f32_16x16x32_f16(a[i], b[j], acc[i][j], 0, 0, 0);
        __syncthreads();
    }
    // spill agg tile -> HX[row][0..127]
    #pragma unroll
    for (int i = 0; i < 2; ++i) {
        int n0 = w * 32 + i * 16 + l4 * 4;
        #pragma unroll
        for (int j = 0; j < 4; ++j) {
            int r = j * 16 + l15;
            f16x4 o;
            o[0] = (_Float16)acc[i][j][0]; o[1] = (_Float16)acc[i][j][1];
            o[2] = (_Float16)acc[i][j][2]; o[3] = (_Float16)acc[i][j][3];
            *(f16x4*)&HX[r][n0] = o;
        }
    }
    // stage x tile -> HX[row][128..255]
    #pragma unroll
    for (int p = 0; p < 8; ++p) {
        int idx = tid + p * 256;
        int r = idx >> 5;
        int f4 = (idx & 31) * 4;
        float4 v = *(const float4*)&x[(size_t)(off + r0 + r) * 128 + f4];
        f16x4 h;
        h[0] = (_Float16)v.x; h[1] = (_Float16)v.y;
        h[2] = (_Float16)v.z; h[3] = (_Float16)v.w;
        *(f16x4*)&HX[r][128 + f4] = h;
    }

    // ---- phase B: K=256 ----
    f32x4 acc2[4][4];
    #pragma unroll
    for (int i = 0; i < 4; ++i)
        #pragma unroll
        for (int j = 0; j < 4; ++j)
            acc2[i][j] = (f32x4){0.f, 0.f, 0.f, 0.f};

    uint4 pw[4];
    #pragma unroll
    for (int p = 0; p < 4; ++p) {
        int idx = tid + p * 256;
        pw[p] = *(const uint4*)&Wh[(size_t)(idx >> 2) * 256 + (idx & 3) * 8];
    }
    #pragma unroll
    for (int s = 0; s < 8; ++s) {
        #pragma unroll
        for (int p = 0; p < 4; ++p) {
            int idx = tid + p * 256;
            *(uint4*)&stage[idx >> 2][(idx & 3) * 8] = pw[p];
        }
        if (s + 1 < 8) {
            int k0 = (s + 1) * 32;
            #pragma unroll
            for (int p = 0; p < 4; ++p) {
                int idx = tid + p * 256;
                pw[p] = *(const uint4*)&Wh[(size_t)(idx >> 2) * 256 + k0 + (idx & 3) * 8];
            }
        }
        __syncthreads();
        f16x8 a[4], b[4];
        #pragma unroll
        for (int i = 0; i < 4; ++i)
            a[i] = *(const f16x8*)&HX[i * 16 + l15][s * 32 + l4 * 8];
        #pragma unroll
        for (int j = 0; j < 4; ++j)
            b[j] = *(const f16x8*)&stage[w * 64 + j * 16 + l15][l4 * 8];
        #pragma unroll
        for (int i = 0; i < 4; ++i)
            #pragma unroll
            for (int j = 0; j < 4; ++j)
                acc2[i][j] = __builtin_amdgcn_mfma_f32_16x16x32_f16(a[i], b[j], acc2[i][j], 0, 0, 0);
        __syncthreads();
    }
    #pragma unroll
    for (int j = 0; j < 4; ++j) {
        int n = w * 64 + j * 16 + l15;
        float bv = bias[n];
        #pragma unroll
        for (int i = 0; i < 4; ++i) {
            #pragma unroll
            for (int r = 0; r < 4; ++r) {
                int m = off + r0 + i * 16 + l4 * 4 + r;
                float v = acc2[i][j][r] + bv;
                out[(size_t)m * 256 + n] = v > 0.f ? v : 0.01f * v;
            }
        }
    }
}

extern "C" void kernel_launch(void* const* d_in, const int* in_sizes, int n_in,
                              void* d_out, int out_size, void* d_ws, size_t ws_size,
                              hipStream_t stream) {
    const float* x     = (const float*)d_in[0];
    const int*   ld    = (const int*)d_in[1];
    const float* am    = (const float*)d_in[2];
    const float* Wl    = (const float*)d_in[3];
    const float* bl    = (const float*)d_in[4];
    const float* gl    = (const float*)d_in[5];
    const float* betal = (const float*)d_in[6];
    const float* ml    = (const float*)d_in[7];
    const float* vl    = (const float*)d_in[8];
    const float* W1    = (const float*)d_in[9];
    const float* b1    = (const float*)d_in[10];
    const float* g1    = (const float*)d_in[11];
    const float* beta1 = (const float*)d_in[12];
    const float* m1    = (const float*)d_in[13];
    const float* v1    = (const float*)d_in[14];
    const float* W2    = (const float*)d_in[15];
    const float* b2    = (const float*)d_in[16];
    const float* g2    = (const float*)d_in[17];
    const float* beta2 = (const float*)d_in[18];
    const float* m2    = (const float*)d_in[19];
    const float* v2    = (const float*)d_in[20];
    float* out = (float*)d_out;

    int M = in_sizes[0] / 128;   // 16384

    char* w = (char*)d_ws;
    int*   offs = (int*)w;
    float* c1   = (float*)(w + 512);
    float* cf   = (float*)(w + 1024);
    _Float16* W1h  = (_Float16*)(w + 4096);
    _Float16* Wch  = (_Float16*)(w + 4096 + 32768);
    _Float16* xhT  = (_Float16*)(w + 4096 + 32768 + 131072);
    _Float16* h2T  = xhT + (size_t)M * 128;

    prep_conv_kernel<<<320, 256, 0, stream>>>(ld,
        Wl, bl, gl, betal, ml, vl,
        W1, b1, g1, beta1, m1, v1,
        W2, b2, g2, beta2, m2, v2,
        offs, c1, cf, W1h, Wch, x, xhT, M);

    fused1_kernel<<<dim3(6, 64), 256, 0, stream>>>(am, xhT, ld, offs, W1h, c1, h2T, M);

    fused2_kernel<<<dim3(6, 64), 256, 0, stream>>>(am, h2T, ld, offs, x, Wch, cf, out, M);
}

// Round 5
// 74.813 us; speedup vs baseline: 1.0428x; 1.0428x over previous
//
#include <hip/hip_runtime.h>

#define EPS 1e-5f

typedef __attribute__((ext_vector_type(4))) float f32x4;
typedef __attribute__((ext_vector_type(8))) _Float16 f16x8;
typedef __attribute__((ext_vector_type(4))) _Float16 f16x4;

// ============ kernel 1: prep (BN-fold, offsets, task table) ∥ convxT ============
__global__ __launch_bounds__(256) void prep_conv_kernel(
    const int* __restrict__ ld,
    const float* __restrict__ Wl, const float* __restrict__ bl,
    const float* __restrict__ gl, const float* __restrict__ betal,
    const float* __restrict__ ml, const float* __restrict__ vl,
    const float* __restrict__ W1, const float* __restrict__ b1,
    const float* __restrict__ g1, const float* __restrict__ beta1,
    const float* __restrict__ m1, const float* __restrict__ v1,
    const float* __restrict__ W2, const float* __restrict__ b2,
    const float* __restrict__ g2, const float* __restrict__ beta2,
    const float* __restrict__ m2, const float* __restrict__ v2,
    int* __restrict__ offs, float* __restrict__ c1, float* __restrict__ cf,
    int* __restrict__ tg, int* __restrict__ tr, int n_tasks,
    _Float16* __restrict__ W1h, _Float16* __restrict__ Wch,
    const float* __restrict__ x, _Float16* __restrict__ XT, int M)
{
    __shared__ __align__(16) _Float16 Tt[128][80];
    int t = threadIdx.x;
    if (blockIdx.x < 256) {
        // ---- convxT: XT[128][M] fp16 from x[M][128] fp32 ----
        int m0 = blockIdx.x * 64;
        #pragma unroll
        for (int p = 0; p < 8; ++p) {
            int idx = t + p * 256;
            int m = idx >> 5;
            int f = (idx & 31) * 4;
            float4 v = *(const float4*)&x[(size_t)(m0 + m) * 128 + f];
            Tt[f + 0][m] = (_Float16)v.x; Tt[f + 1][m] = (_Float16)v.y;
            Tt[f + 2][m] = (_Float16)v.z; Tt[f + 3][m] = (_Float16)v.w;
        }
        __syncthreads();
        #pragma unroll
        for (int p = 0; p < 4; ++p) {
            int idx = t + p * 256;
            int f = idx >> 3;
            int m8 = (idx & 7) * 8;
            uint4 v = *(const uint4*)&Tt[f][m8];
            *(uint4*)&XT[(size_t)f * M + m0 + m8] = v;
        }
    } else {
        int b = blockIdx.x - 256;
        int gt = b * 256 + t;
        const int gsize = 64 * 256;
        if (b == 0) {
            if (t < 64) {
                int s = 0;
                for (int i = 0; i < t; ++i) s += ld[i];
                offs[t] = s;
            }
            if (t < 128) {
                float s1 = g1[t] * rsqrtf(v1[t] + EPS);
                c1[t] = (b1[t] - m1[t]) * s1 + beta1[t];
            }
            if (t < 256) {
                float s2 = g2[t] * rsqrtf(v2[t] + EPS);
                float sl = gl[t] * rsqrtf(vl[t] + EPS);
                cf[t] = (b2[t] - m2[t]) * s2 + beta2[t] + (bl[t] - ml[t]) * sl + betal[t];
            }
            // task table: 32-row tiles over the ragged rows
            for (int t2 = t; t2 < n_tasks; t2 += 256) {
                int rem = t2, g = 0;
                while (true) {
                    int n = ld[g] >> 5;   // tiles of 32 rows
                    if (rem < n) break;
                    rem -= n; ++g;
                }
                tg[t2] = g;
                tr[t2] = rem << 5;
            }
        }
        for (int idx = gt; idx < 128 * 128; idx += gsize) {
            int n = idx >> 7;
            float s1 = g1[n] * rsqrtf(v1[n] + EPS);
            W1h[idx] = (_Float16)(W1[idx] * s1);
        }
        for (int idx = gt; idx < 256 * 256; idx += gsize) {
            int n = idx >> 8, k = idx & 255;
            float v;
            if (k < 128) {
                float s2 = g2[n] * rsqrtf(v2[n] + EPS);
                v = W2[n * 128 + k] * s2;
            } else {
                float sl = gl[n] * rsqrtf(vl[n] + EPS);
                v = Wl[n * 128 + (k - 128)] * sl;
            }
            Wch[idx] = (_Float16)v;
        }
    }
}

// ============ kernel 2: fused agg1 + lin1 -> h2T, wave-task version ============
// Block = 32 rows of one graph. Waves (w>>1) pick 16-row tile, (w&1) picks feat half.
// Phase A (per wave): h1[16m x 64f] = am-rows x XT, operands direct from global.
// Exchange halves via LDS (one barrier). Phase B: h2T[n][m]=relu(h1 @ W1h^T + c1).
__global__ __launch_bounds__(256) void fused1w_kernel(
    const float* __restrict__ am, const _Float16* __restrict__ XT,
    const int* __restrict__ ld, const int* __restrict__ offs,
    const int* __restrict__ tg, const int* __restrict__ tr,
    const _Float16* __restrict__ Wh, const float* __restrict__ bias,
    _Float16* __restrict__ outT, int M)
{
    int task = blockIdx.x;
    int g = tg[task];
    int l = ld[g];
    int off = offs[g];
    const float* A = am + (size_t)g * (512 * 512);

    int tid = threadIdx.x;
    int lane = tid & 63;
    int w = tid >> 6;
    int l15 = lane & 15;
    int l4 = lane >> 4;
    int half = w & 1;
    int rt = w >> 1;
    int r0 = tr[task] + rt * 16;
    int fb = half * 64;
    int gm0 = off + r0;

    __shared__ __align__(16) _Float16 Hs[2][16][136];

    // ---- phase A ----
    f32x4 acc[4];
    #pragma unroll
    for (int i = 0; i < 4; ++i) acc[i] = (f32x4){0.f, 0.f, 0.f, 0.f};

    const size_t amrow = (size_t)(r0 + l15) * 512;
    uint4 pa[4]; float4 pb0, pb1;
    #pragma unroll
    for (int i = 0; i < 4; ++i)
        pa[i] = *(const uint4*)&XT[(size_t)(fb + i * 16 + l15) * M + off + l4 * 8];
    pb0 = *(const float4*)&A[amrow + l4 * 8];
    pb1 = *(const float4*)&A[amrow + l4 * 8 + 4];

    int nk = l >> 5;
    for (int s = 0; s < nk; ++s) {
        uint4 ca[4] = {pa[0], pa[1], pa[2], pa[3]};
        float4 cb0 = pb0, cb1 = pb1;
        if (s + 1 < nk) {
            int k0 = (s + 1) * 32;
            #pragma unroll
            for (int i = 0; i < 4; ++i)
                pa[i] = *(const uint4*)&XT[(size_t)(fb + i * 16 + l15) * M + off + k0 + l4 * 8];
            pb0 = *(const float4*)&A[amrow + k0 + l4 * 8];
            pb1 = *(const float4*)&A[amrow + k0 + l4 * 8 + 4];
        }
        f16x8 bf;
        bf[0] = (_Float16)cb0.x; bf[1] = (_Float16)cb0.y;
        bf[2] = (_Float16)cb0.z; bf[3] = (_Float16)cb0.w;
        bf[4] = (_Float16)cb1.x; bf[5] = (_Float16)cb1.y;
        bf[6] = (_Float16)cb1.z; bf[7] = (_Float16)cb1.w;
        #pragma unroll
        for (int i = 0; i < 4; ++i) {
            f16x8 av = *(f16x8*)&ca[i];
            acc[i] = __builtin_amdgcn_mfma_f32_16x16x32_f16(av, bf, acc[i], 0, 0, 0);
        }
    }
    // spill: lane holds m = l15 (local), feat = fb + i*16 + l4*4 + r
    #pragma unroll
    for (int i = 0; i < 4; ++i) {
        f16x4 o;
        #pragma unroll
        for (int r = 0; r < 4; ++r) o[r] = (_Float16)acc[i][r];
        *(f16x4*)&Hs[rt][l15][fb + i * 16 + l4 * 4] = o;
    }
    __syncthreads();

    // ---- phase B: K=128, out-feats half = 64 ----
    f32x4 acc2[4];
    #pragma unroll
    for (int j = 0; j < 4; ++j) acc2[j] = (f32x4){0.f, 0.f, 0.f, 0.f};
    int nb = half * 64;
    #pragma unroll
    for (int s = 0; s < 4; ++s) {
        int k0 = s * 32;
        f16x8 a = *(const f16x8*)&Hs[rt][l15][k0 + l4 * 8];
        #pragma unroll
        for (int j = 0; j < 4; ++j) {
            f16x8 b = *(const f16x8*)&Wh[(size_t)(nb + j * 16 + l15) * 128 + k0 + l4 * 8];
            acc2[j] = __builtin_amdgcn_mfma_f32_16x16x32_f16(a, b, acc2[j], 0, 0, 0);
        }
    }
    // D: l15-dim = n (b rows), reg-dim = m (a rows) -> h2T[n][gm0 + l4*4 + r]
    #pragma unroll
    for (int j = 0; j < 4; ++j) {
        int n = nb + j * 16 + l15;
        float bv = bias[n];
        f16x4 o;
        #pragma unroll
        for (int r = 0; r < 4; ++r) {
            float v = acc2[j][r] + bv;
            o[r] = (_Float16)(v > 0.f ? v : 0.f);
        }
        *(f16x4*)&outT[(size_t)n * M + gm0 + l4 * 4] = o;
    }
}

// ============ kernel 3: fused agg2 + final -> out fp32, wave-task version ============
__global__ __launch_bounds__(256) void fused2w_kernel(
    const float* __restrict__ am, const _Float16* __restrict__ H2T,
    const int* __restrict__ ld, const int* __restrict__ offs,
    const int* __restrict__ tg, const int* __restrict__ tr,
    const float* __restrict__ x, const _Float16* __restrict__ Wch,
    const float* __restrict__ bias, float* __restrict__ out, int M)
{
    int task = blockIdx.x;
    int g = tg[task];
    int l = ld[g];
    int off = offs[g];
    const float* A = am + (size_t)g * (512 * 512);

    int tid = threadIdx.x;
    int lane = tid & 63;
    int w = tid >> 6;
    int l15 = lane & 15;
    int l4 = lane >> 4;
    int half = w & 1;
    int rt = w >> 1;
    int r0 = tr[task] + rt * 16;
    int fb = half * 64;
    int gm0 = off + r0;

    __shared__ __align__(16) _Float16 Hs[2][16][136];

    // ---- phase A: agg2 from h2T ----
    f32x4 acc[4];
    #pragma unroll
    for (int i = 0; i < 4; ++i) acc[i] = (f32x4){0.f, 0.f, 0.f, 0.f};

    const size_t amrow = (size_t)(r0 + l15) * 512;
    uint4 pa[4]; float4 pb0, pb1;
    #pragma unroll
    for (int i = 0; i < 4; ++i)
        pa[i] = *(const uint4*)&H2T[(size_t)(fb + i * 16 + l15) * M + off + l4 * 8];
    pb0 = *(const float4*)&A[amrow + l4 * 8];
    pb1 = *(const float4*)&A[amrow + l4 * 8 + 4];

    int nk = l >> 5;
    for (int s = 0; s < nk; ++s) {
        uint4 ca[4] = {pa[0], pa[1], pa[2], pa[3]};
        float4 cb0 = pb0, cb1 = pb1;
        if (s + 1 < nk) {
            int k0 = (s + 1) * 32;
            #pragma unroll
            for (int i = 0; i < 4; ++i)
                pa[i] = *(const uint4*)&H2T[(size_t)(fb + i * 16 + l15) * M + off + k0 + l4 * 8];
            pb0 = *(const float4*)&A[amrow + k0 + l4 * 8];
            pb1 = *(const float4*)&A[amrow + k0 + l4 * 8 + 4];
        }
        f16x8 bf;
        bf[0] = (_Float16)cb0.x; bf[1] = (_Float16)cb0.y;
        bf[2] = (_Float16)cb0.z; bf[3] = (_Float16)cb0.w;
        bf[4] = (_Float16)cb1.x; bf[5] = (_Float16)cb1.y;
        bf[6] = (_Float16)cb1.z; bf[7] = (_Float16)cb1.w;
        #pragma unroll
        for (int i = 0; i < 4; ++i) {
            f16x8 av = *(f16x8*)&ca[i];
            acc[i] = __builtin_amdgcn_mfma_f32_16x16x32_f16(av, bf, acc[i], 0, 0, 0);
        }
    }
    #pragma unroll
    for (int i = 0; i < 4; ++i) {
        f16x4 o;
        #pragma unroll
        for (int r = 0; r < 4; ++r) o[r] = (_Float16)acc[i][r];
        *(f16x4*)&Hs[rt][l15][fb + i * 16 + l4 * 4] = o;
    }
    __syncthreads();

    // ---- phase B: K=256 ([h3 | x]), out-feats half = 128 ----
    f32x4 acc2[8];
    #pragma unroll
    for (int j = 0; j < 8; ++j) acc2[j] = (f32x4){0.f, 0.f, 0.f, 0.f};
    int nb = half * 128;
    #pragma unroll
    for (int s = 0; s < 8; ++s) {
        int k0 = s * 32;
        f16x8 a;
        if (s < 4) {
            a = *(const f16x8*)&Hs[rt][l15][k0 + l4 * 8];
        } else {
            const float* xr = &x[(size_t)(gm0 + l15) * 128 + (k0 - 128) + l4 * 8];
            float4 v0 = *(const float4*)xr;
            float4 v1 = *(const float4*)(xr + 4);
            a[0] = (_Float16)v0.x; a[1] = (_Float16)v0.y;
            a[2] = (_Float16)v0.z; a[3] = (_Float16)v0.w;
            a[4] = (_Float16)v1.x; a[5] = (_Float16)v1.y;
            a[6] = (_Float16)v1.z; a[7] = (_Float16)v1.w;
        }
        #pragma unroll
        for (int j = 0; j < 8; ++j) {
            f16x8 b = *(const f16x8*)&Wch[(size_t)(nb + j * 16 + l15) * 256 + k0 + l4 * 8];
            acc2[j] = __builtin_amdgcn_mfma_f32_16x16x32_f16(a, b, acc2[j], 0, 0, 0);
        }
    }
    #pragma unroll
    for (int j = 0; j < 8; ++j) {
        int n = nb + j * 16 + l15;
        float bv = bias[n];
        #pragma unroll
        for (int r = 0; r < 4; ++r) {
            int m = gm0 + l4 * 4 + r;
            float v = acc2[j][r] + bv;
            out[(size_t)m * 256 + n] = v > 0.f ? v : 0.01f * v;
        }
    }
}

extern "C" void kernel_launch(void* const* d_in, const int* in_sizes, int n_in,
                              void* d_out, int out_size, void* d_ws, size_t ws_size,
                              hipStream_t stream) {
    const float* x     = (const float*)d_in[0];
    const int*   ld    = (const int*)d_in[1];
    const float* am    = (const float*)d_in[2];
    const float* Wl    = (const float*)d_in[3];
    const float* bl    = (const float*)d_in[4];
    const float* gl    = (const float*)d_in[5];
    const float* betal = (const float*)d_in[6];
    const float* ml    = (const float*)d_in[7];
    const float* vl    = (const float*)d_in[8];
    const float* W1    = (const float*)d_in[9];
    const float* b1    = (const float*)d_in[10];
    const float* g1    = (const float*)d_in[11];
    const float* beta1 = (const float*)d_in[12];
    const float* m1    = (const float*)d_in[13];
    const float* v1    = (const float*)d_in[14];
    const float* W2    = (const float*)d_in[15];
    const float* b2    = (const float*)d_in[16];
    const float* g2    = (const float*)d_in[17];
    const float* beta2 = (const float*)d_in[18];
    const float* m2    = (const float*)d_in[19];
    const float* v2    = (const float*)d_in[20];
    float* out = (float*)d_out;

    int M = in_sizes[0] / 128;   // 16384
    int n_tasks = M / 32;        // 512

    char* w = (char*)d_ws;
    int*   offs = (int*)w;                         // 64 int
    float* c1   = (float*)(w + 512);               // 128 f
    float* cf   = (float*)(w + 1024);              // 256 f
    int*   tg   = (int*)(w + 2048);                // 512 int
    int*   tr   = (int*)(w + 4096);                // 512 int
    _Float16* W1h = (_Float16*)(w + 8192);         // 16384 h
    _Float16* Wch = (_Float16*)(w + 8192 + 32768); // 65536 h
    _Float16* xhT = (_Float16*)(w + 8192 + 32768 + 131072);
    _Float16* h2T = xhT + (size_t)M * 128;

    prep_conv_kernel<<<320, 256, 0, stream>>>(ld,
        Wl, bl, gl, betal, ml, vl,
        W1, b1, g1, beta1, m1, v1,
        W2, b2, g2, beta2, m2, v2,
        offs, c1, cf, tg, tr, n_tasks, W1h, Wch, x, xhT, M);

    fused1w_kernel<<<n_tasks, 256, 0, stream>>>(am, xhT, ld, offs, tg, tr, W1h, c1, h2T, M);

    fused2w_kernel<<<n_tasks, 256, 0, stream>>>(am, h2T, ld, offs, tg, tr, x, Wch, cf, out, M);
}